// Round 3
// baseline (549.056 us; speedup 1.0000x reference)
//
#include <hip/hip_runtime.h>
#include <math.h>

#define DIM 16        // 2^Q, Q=4
#define BATCH 2       // B from setup_inputs
#define TT 128        // tokens per block in projection kernel

typedef float f32x4  __attribute__((ext_vector_type(4)));
typedef float f32x16 __attribute__((ext_vector_type(16)));

// ---------------------------------------------------------------------------
// Kernel A: embedding gather + normalize + noisy circuit + mask select.
// One thread per token (B*S = 4096 threads). 64-thread blocks -> 64 CUs busy.
// ---------------------------------------------------------------------------
__global__ void quantum_state_kernel(const int* __restrict__ ids,
                                     const int* __restrict__ mask,
                                     const float* __restrict__ W_embed,
                                     const float* __restrict__ gates,
                                     float* __restrict__ proc,
                                     int B, int S, int depth) {
    extern __shared__ float g[];                 // depth*DIM*DIM gate coeffs
    const int tid = threadIdx.x;
    const int ng = depth * DIM * DIM;
    for (int i = tid; i < ng; i += blockDim.x) g[i] = gates[i];
    __syncthreads();

    const int t = blockIdx.x * blockDim.x + tid; // token index b*S + s
    const int total = B * S;
    if (t >= total) return;
    const int s_idx = t % S;

    // embedding lookup + normalize: emb = row / (||row|| + 1e-12)
    const int id = ids[t];
    f32x16 e = *(const f32x16*)(W_embed + (size_t)id * DIM);
    float ss = 0.f;
#pragma unroll
    for (int k = 0; k < DIM; ++k) ss += e[k] * e[k];
    float inv = 1.0f / (sqrtf(ss) + 1e-12f);
#pragma unroll
    for (int k = 0; k < DIM; ++k) e[k] *= inv;

    // noisy circuit
    f32x16 st = e;
    for (int l = 0; l < depth; ++l) {
        const float* gl = g + l * DIM * DIM;
        f32x16 ns;
#pragma unroll
        for (int ei = 0; ei < DIM; ++ei) {
            float acc = 0.f;
#pragma unroll
            for (int d = 0; d < DIM; ++d) acc += gl[ei * DIM + d] * st[d];
            ns[ei] = acc;
        }
        ss = 0.f;
#pragma unroll
        for (int k = 0; k < DIM; ++k) {
            float v = ns[k] * 0.99f;              // decoherence (1-0.01)
            v = 0.99f * v + 0.000625f;            // depolarization 0.99*x + 0.01/16
            ns[k] = v;
            ss += v * v;
        }
        inv = 1.0f / (sqrtf(ss) + 1e-12f);
#pragma unroll
        for (int k = 0; k < DIM; ++k) st[k] = ns[k] * inv;
    }
#pragma unroll
    for (int k = 0; k < DIM; ++k) st[k] = 0.99f * st[k] + 0.000625f;  // measurement error

    // apply only if mask[:, s] all nonzero
    bool apply = true;
    for (int b = 0; b < B; ++b) apply = apply && (mask[b * S + s_idx] != 0);

    *(f32x16*)(proc + (size_t)t * DIM) = apply ? st : e;   // 4x dwordx4 store
}

// ---------------------------------------------------------------------------
// Kernel B: out[t, v] = dot(proc[t,:], W_out[v,:]) + b_out[v]
// Block = 256 threads handles TT=128 tokens x 1024 vocab entries.
// Rationale for TT=128: each f32x16 W_out load has a 256-B inter-lane stride
// -> 64 distinct cache lines PER VMEM INSTRUCTION (worst case for the TA/L1
// pipe; the 64-KB per-y-slice working set also misses the 32-KB L1). That
// scatter cost is paid once per (x-block, y-slice); TT 32->128 cuts x-blocks
// 128->32, so W_out scatter traffic drops 4x (262->65 MB) while 1024 blocks
// (4/CU, 16 waves/CU) still give enough TLP for the store stream.
// Token-state load is software-pipelined one iteration ahead so its latency
// hides under the previous token's 64 FMAs + store.
// ---------------------------------------------------------------------------
__global__ __launch_bounds__(256) void out_proj_kernel(
        const float* __restrict__ proc,
        const float* __restrict__ W_out,
        const float* __restrict__ b_out,
        float* __restrict__ out,
        int V, int total_tokens) {
    const int tid = threadIdx.x;
    const int t0 = blockIdx.x * TT;
    const int v0 = blockIdx.y * 1024 + tid * 4;
    if (v0 >= V) return;           // V % 4 == 0 => v0..v0+3 all valid below

    // 4 vocab rows, 64 VGPRs, statically indexed only (SSA ext_vectors)
    const f32x16 w0 = *(const f32x16*)(W_out + (size_t)(v0 + 0) * DIM);
    const f32x16 w1 = *(const f32x16*)(W_out + (size_t)(v0 + 1) * DIM);
    const f32x16 w2 = *(const f32x16*)(W_out + (size_t)(v0 + 2) * DIM);
    const f32x16 w3 = *(const f32x16*)(W_out + (size_t)(v0 + 3) * DIM);
    const f32x4 bias = *(const f32x4*)(b_out + v0);   // v0 % 4 == 0 -> 16B aligned

    // wave-uniform address (blockIdx.x + loop counter only) -> scalar loads
    f32x16 sv = *(const f32x16*)(proc + (size_t)t0 * DIM);

#pragma unroll 2
    for (int tk = 0; tk < TT; ++tk) {
        const int t = t0 + tk;
        if (t >= total_tokens) break;
        // prefetch next token's state before this token's FMAs
        f32x16 nxt = sv;
        if (tk + 1 < TT && t + 1 < total_tokens)
            nxt = *(const f32x16*)(proc + (size_t)(t + 1) * DIM);

        float a0 = bias[0], a1 = bias[1], a2 = bias[2], a3 = bias[3];
#pragma unroll
        for (int k = 0; k < DIM; ++k) {
            a0 = fmaf(sv[k], w0[k], a0);
            a1 = fmaf(sv[k], w1[k], a1);
            a2 = fmaf(sv[k], w2[k], a2);
            a3 = fmaf(sv[k], w3[k], a3);
        }
        f32x4 r; r[0] = a0; r[1] = a1; r[2] = a2; r[3] = a3;
        __builtin_nontemporal_store(r, (f32x4*)(out + (size_t)t * V + v0));
        sv = nxt;
    }
}

extern "C" void kernel_launch(void* const* d_in, const int* in_sizes, int n_in,
                              void* d_out, int out_size, void* d_ws, size_t ws_size,
                              hipStream_t stream) {
    const int*   ids    = (const int*)  d_in[0];  // [B,S]
    const int*   mask   = (const int*)  d_in[1];  // [B,S]
    const float* W_emb  = (const float*)d_in[2];  // [V,16]
    const float* gates  = (const float*)d_in[3];  // [depth,16,16]
    const float* W_out  = (const float*)d_in[4];  // [V,16]
    const float* b_out  = (const float*)d_in[5];  // [V]
    float* out = (float*)d_out;

    const int B = BATCH;
    const int total = in_sizes[0];          // B*S
    const int S = total / B;
    const int V = in_sizes[5];
    const int depth = in_sizes[3] / (DIM * DIM);

    float* proc = (float*)d_ws;             // [total, DIM] scratch (256 KB)

    // Kernel A: tiny — compute processed states (64-thread blocks -> 64 CUs)
    {
        dim3 block(64);
        dim3 grid((total + 63) / 64);
        size_t shmem = (size_t)depth * DIM * DIM * sizeof(float);
        quantum_state_kernel<<<grid, block, shmem, stream>>>(
            ids, mask, W_emb, gates, proc, B, S, depth);
    }

    // Kernel B: projection, write-bound
    {
        dim3 block(256);
        dim3 grid((total + TT - 1) / TT, (V + 1023) / 1024);
        out_proj_kernel<<<grid, block, 0, stream>>>(proc, W_out, b_out, out, V, total);
    }
}